// Round 5
// baseline (418.554 us; speedup 1.0000x reference)
//
#include <hip/hip_runtime.h>

// ---------------------------------------------------------------------------
// GIN 3-layer forward on MI355X (gfx950).
//   - features/weights quantized to bf16 once per call (f32 accumulate)
//   - CSR built by dst-bucketing with LDS-staged scatter:
//       k_scatter: 48 blocks, 782 LDS bins/block, full-64B-line flushes to
//                  per-bucket global cells (kills partial-line write amplif.)
//       k_bscan:   exclusive scan of bucket totals
//       k_build:   per-bucket LDS histogram + scan -> rp, slotting -> csr
//   - segment-sum gather: 16 lanes/node, bf16x8 loads, f32 accum
//   - MLP: MFMA 16x16x32 bf16, BM=128 block, 4 waves (2x2 of 64x64),
//     128 KB LDS, XOR-swizzled
//   - layer 1 only on active set = roots U in-neighbors(roots)
//   - layer 2 only at the 1024 roots
//   NOTE: packing assumes N <= 2^17; LDS bin arrays assume <= 784 buckets
//         (N <= 100352). Both hold for this problem (N = 100000).
// ---------------------------------------------------------------------------

typedef __bf16  bf16x8 __attribute__((ext_vector_type(8)));
typedef float   f32x4  __attribute__((ext_vector_type(4)));

#define SWZ(r, c) ((c) ^ ((r) & 7))   // c = 16B-chunk index within a 256B row

#define NBINS_MAX 784     // LDS bins (>= (N+127)/128)
#define BCAP      28      // words per LDS bin
#define CAP       4096    // words per global bucket cell (mean ~2048)
#define SCAT_BLK  48      // scatter blocks (few -> small tails)

// ---------------- conversion kernels ----------------
__global__ __launch_bounds__(256) void k_cvt_x(const float4* __restrict__ in,
                                               unsigned short* __restrict__ outb,
                                               long n8) {
    long i = (long)blockIdx.x * 256 + threadIdx.x;
    if (i >= n8) return;
    float4 a = in[2 * i], b = in[2 * i + 1];
    bf16x8 v;
    v[0] = (__bf16)a.x; v[1] = (__bf16)a.y; v[2] = (__bf16)a.z; v[3] = (__bf16)a.w;
    v[4] = (__bf16)b.x; v[5] = (__bf16)b.y; v[6] = (__bf16)b.z; v[7] = (__bf16)b.w;
    *(bf16x8*)&outb[i * 8] = v;
}

// wT[n][k] = (bf16) w[k][n]   (128x128)
__global__ __launch_bounds__(256) void k_cvt_w(const float* __restrict__ w,
                                               unsigned short* __restrict__ wT) {
    int i = blockIdx.x * 256 + threadIdx.x;   // 16384
    int k = i >> 7, n = i & 127;
    *(__bf16*)&wT[n * 128 + k] = (__bf16)w[i];
}

// ---------------- LDS-staged bucketed scatter ----------------
// gcnt: one counter per bucket, padded to 64B (index b*16).
__global__ __launch_bounds__(256) void k_scatter(const int* __restrict__ src,
                                                 const int* __restrict__ dst,
                                                 int* __restrict__ gcnt,
                                                 unsigned* __restrict__ ebuf,
                                                 int e, int nbins) {
    __shared__ unsigned lbuf[NBINS_MAX * BCAP];   // 87.8 KB
    __shared__ int lcnt[NBINS_MAX];
    const int t = threadIdx.x;
    for (int b = t; b < nbins; b += 256) lcnt[b] = 0;
    __syncthreads();

    const int per = (e + SCAT_BLK - 1) / SCAT_BLK;
    const int beg = blockIdx.x * per;
    const int end = (beg + per < e) ? beg + per : e;

    for (int tile = beg; tile < end; tile += 2048) {
        const int tend = (tile + 2048 < end) ? tile + 2048 : end;
        for (int i = tile + t; i < tend; i += 256) {
            int d = dst[i];
            unsigned w = (unsigned)src[i] | ((unsigned)(d & 127) << 17);
            int b = d >> 7;
            int p = atomicAdd(&lcnt[b], 1);
            if (p < BCAP) {
                lbuf[b * BCAP + p] = w;
            } else {                                  // rare spill (~1e-6)
                int g = atomicAdd(&gcnt[b * 16], 1);
                if (g < CAP) ebuf[(size_t)b * CAP + g] = w;
            }
        }
        __syncthreads();
        // flush multiples of 16 words (full 64B lines) per bin
        for (int b = t; b < nbins; b += 256) {
            int cnt = lcnt[b]; if (cnt > BCAP) cnt = BCAP;
            int nf = cnt & ~15;
            if (nf > 0) {
                int base = atomicAdd(&gcnt[b * 16], nf);
                unsigned* cell = ebuf + (size_t)b * CAP;
                for (int j = 0; j < nf; ++j) {
                    int g = base + j;
                    if (g < CAP) cell[g] = lbuf[b * BCAP + j];
                }
                int r = cnt - nf;
                for (int j = 0; j < r; ++j)
                    lbuf[b * BCAP + j] = lbuf[b * BCAP + nf + j];
                lcnt[b] = r;
            } else {
                lcnt[b] = cnt;
            }
        }
        __syncthreads();
    }
    // tails (< 16 words per bin) through the shared frontier
    for (int b = t; b < nbins; b += 256) {
        int r = lcnt[b]; if (r > BCAP) r = BCAP;
        if (r > 0) {
            int base = atomicAdd(&gcnt[b * 16], r);
            unsigned* cell = ebuf + (size_t)b * CAP;
            for (int j = 0; j < r; ++j) {
                int g = base + j;
                if (g < CAP) cell[g] = lbuf[b * BCAP + j];
            }
        }
    }
}

// one block: exclusive scan of nb bucket totals (nb <= 1024); also rp[n]=e
__global__ __launch_bounds__(1024) void k_bscan(const int* __restrict__ gcnt,
                                                int* __restrict__ boff,
                                                int* __restrict__ rp,
                                                int nb, int n, int e) {
    __shared__ int sh[1024];
    int t = threadIdx.x;
    int s = 0;
    if (t < nb) { s = gcnt[t * 16]; if (s > CAP) s = CAP; }
    sh[t] = s;
    __syncthreads();
    for (int off = 1; off < 1024; off <<= 1) {
        int u = (t >= off) ? sh[t - off] : 0;
        __syncthreads();
        sh[t] += u;
        __syncthreads();
    }
    if (t < nb) boff[t] = (t == 0) ? 0 : sh[t - 1];
    if (t == 0) rp[n] = e;
}

// one block per bucket: LDS histogram -> scan -> rp write -> csr slotting
__global__ __launch_bounds__(256) void k_build(const unsigned* __restrict__ ebuf,
                                               const int* __restrict__ gcnt,
                                               const int* __restrict__ boff,
                                               int* __restrict__ rp,
                                               int* __restrict__ csr, int n) {
    __shared__ int bins[128];
    __shared__ int incl[128];
    __shared__ int cur[128];
    int b = blockIdx.x, t = threadIdx.x;
    if (t < 128) bins[t] = 0;
    __syncthreads();
    int c = gcnt[b * 16]; if (c > CAP) c = CAP;
    const unsigned* seg = ebuf + ((size_t)b * CAP);
    for (int j = t; j < c; j += 256)
        atomicAdd(&bins[(seg[j] >> 17) & 127], 1);
    __syncthreads();
    if (t < 128) incl[t] = bins[t];
    __syncthreads();
    for (int off = 1; off < 128; off <<= 1) {
        int u = (t < 128 && t >= off) ? incl[t - off] : 0;
        __syncthreads();
        if (t < 128) incl[t] += u;
        __syncthreads();
    }
    int base = boff[b];
    if (t < 128) {
        int ex = (t == 0) ? 0 : incl[t - 1];
        cur[t] = ex;
        int node = b * 128 + t;
        if (node < n) rp[node] = base + ex;
    }
    __syncthreads();
    for (int j = t; j < c; j += 256) {
        unsigned w = seg[j];
        int slot = atomicAdd(&cur[(w >> 17) & 127], 1);
        csr[base + slot] = (int)(w & 0x1FFFF);
    }
}

// ---------------- active set (roots + their in-neighbors) ----------------
__global__ void k_flag(const int* __restrict__ roots, int nr,
                       const int* __restrict__ rp, const int* __restrict__ csr,
                       int* __restrict__ af) {
    int i = blockIdx.x * blockDim.x + threadIdx.x;
    if (i >= nr) return;
    int r = roots[i];
    af[r] = 1;
    int e = rp[r + 1];
    for (int k = rp[r]; k < e; ++k) af[csr[k]] = 1;
}

__global__ void k_compact(const int* __restrict__ af, int* __restrict__ list,
                          int* __restrict__ cnt, int n) {
    int i = blockIdx.x * blockDim.x + threadIdx.x;
    if (i < n && af[i]) {
        int p = atomicAdd(cnt, 1);
        list[p] = i;
    }
}

// ---------------- segment sum (bf16 in, bf16 out, f32 accumulate) ----------
__global__ __launch_bounds__(256) void k_segsum(const unsigned short* __restrict__ xb,
                                                const int* __restrict__ rp,
                                                const int* __restrict__ csr,
                                                unsigned short* __restrict__ agg,
                                                const int* __restrict__ list,
                                                const int* __restrict__ cntp, int n) {
    int gid = blockIdx.x * 256 + threadIdx.x;
    int j = gid >> 4, lane = gid & 15;
    int rows = n;
    if (cntp) { int c = *cntp; rows = c < n ? c : n; }
    if (j >= rows) return;
    int node = list ? list[j] : j;
    int b = rp[node], e = rp[node + 1];
    float s0[8], s1[8];
#pragma unroll
    for (int q = 0; q < 8; ++q) { s0[q] = 0.f; s1[q] = 0.f; }
    int k = b;
    for (; k + 1 < e; k += 2) {
        bf16x8 v0 = *(const bf16x8*)&xb[(size_t)csr[k]     * 128 + lane * 8];
        bf16x8 v1 = *(const bf16x8*)&xb[(size_t)csr[k + 1] * 128 + lane * 8];
#pragma unroll
        for (int q = 0; q < 8; ++q) { s0[q] += (float)v0[q]; s1[q] += (float)v1[q]; }
    }
    if (k < e) {
        bf16x8 v0 = *(const bf16x8*)&xb[(size_t)csr[k] * 128 + lane * 8];
#pragma unroll
        for (int q = 0; q < 8; ++q) s0[q] += (float)v0[q];
    }
    bf16x8 o;
#pragma unroll
    for (int q = 0; q < 8; ++q) o[q] = (__bf16)(s0[q] + s1[q]);
    *(bf16x8*)&agg[(size_t)j * 128 + lane * 8] = o;
}

// ---------------- fused MLP: relu( relu(z@w1+b1) @ w2 + b2 ), z=(1+eps)x+agg
__global__ __launch_bounds__(256) void k_mlp(const unsigned short* __restrict__ xb,
                                             const unsigned short* __restrict__ aggb,
                                             const float* __restrict__ epsp,
                                             const unsigned short* __restrict__ w1T,
                                             const float* __restrict__ b1,
                                             const unsigned short* __restrict__ w2T,
                                             const float* __restrict__ b2,
                                             unsigned short* __restrict__ out,
                                             const int* __restrict__ list,
                                             const int* __restrict__ cntp, int nrows) {
    __shared__ unsigned short zt [128 * 128];
    __shared__ unsigned short ht [128 * 128];
    __shared__ unsigned short w1s[128 * 128];
    __shared__ unsigned short w2s[128 * 128];
    const int t = threadIdx.x;
    int rows = nrows;
    if (cntp) { int c = *cntp; rows = c < nrows ? c : nrows; }
    const int row0 = blockIdx.x * 128;
    if (row0 >= rows) return;
    const float epsv = 1.0f + epsp[0];

    for (int i = t; i < 2048; i += 256) {
        int r = i >> 4, c = i & 15;
        int d = r * 128 + SWZ(r, c) * 8;
        *(f32x4*)&w1s[d] = *(const f32x4*)&w1T[i * 8];
        *(f32x4*)&w2s[d] = *(const f32x4*)&w2T[i * 8];
    }
    for (int i = t; i < 2048; i += 256) {
        int r = i >> 4, c = i & 15;
        int g = row0 + r;
        bf16x8 zv;
        if (g < rows) {
            int node = list ? list[g] : g;
            bf16x8 xv = *(const bf16x8*)&xb  [(size_t)node * 128 + c * 8];
            bf16x8 av = *(const bf16x8*)&aggb[(size_t)g    * 128 + c * 8];
#pragma unroll
            for (int q = 0; q < 8; ++q)
                zv[q] = (__bf16)(epsv * (float)xv[q] + (float)av[q]);
        } else {
#pragma unroll
            for (int q = 0; q < 8; ++q) zv[q] = (__bf16)0.0f;
        }
        *(bf16x8*)&zt[r * 128 + SWZ(r, c) * 8] = zv;
    }
    __syncthreads();

    const int lane = t & 63;
    const int wm = (t >> 7) & 1, wn = (t >> 6) & 1;
    const int lr = lane & 15, lk = lane >> 4;

    f32x4 zero4 = {0.f, 0.f, 0.f, 0.f};
    f32x4 acc[4][4];
#pragma unroll
    for (int mt = 0; mt < 4; ++mt)
#pragma unroll
        for (int nt = 0; nt < 4; ++nt) acc[mt][nt] = zero4;

#pragma unroll
    for (int kb = 0; kb < 4; ++kb) {
        const int c = kb * 4 + lk;
        bf16x8 a[4];
#pragma unroll
        for (int mt = 0; mt < 4; ++mt) {
            int r = wm * 64 + mt * 16 + lr;
            a[mt] = *(const bf16x8*)&zt[r * 128 + SWZ(r, c) * 8];
        }
#pragma unroll
        for (int nt = 0; nt < 4; ++nt) {
            int r = wn * 64 + nt * 16 + lr;
            bf16x8 b = *(const bf16x8*)&w1s[r * 128 + SWZ(r, c) * 8];
#pragma unroll
            for (int mt = 0; mt < 4; ++mt)
                acc[mt][nt] = __builtin_amdgcn_mfma_f32_16x16x32_bf16(a[mt], b, acc[mt][nt], 0, 0, 0);
        }
    }

#pragma unroll
    for (int nt = 0; nt < 4; ++nt) {
        int col = wn * 64 + nt * 16 + lr;
        float bv = b1[col];
        int c8 = col >> 3, ci = col & 7;
#pragma unroll
        for (int mt = 0; mt < 4; ++mt)
#pragma unroll
            for (int q = 0; q < 4; ++q) {
                int hr = wm * 64 + mt * 16 + lk * 4 + q;
                float hv = fmaxf(acc[mt][nt][q] + bv, 0.f);
                *(__bf16*)&ht[hr * 128 + SWZ(hr, c8) * 8 + ci] = (__bf16)hv;
            }
    }
    __syncthreads();

    f32x4 acc2[4][4];
#pragma unroll
    for (int mt = 0; mt < 4; ++mt)
#pragma unroll
        for (int nt = 0; nt < 4; ++nt) acc2[mt][nt] = zero4;
#pragma unroll
    for (int kb = 0; kb < 4; ++kb) {
        const int c = kb * 4 + lk;
        bf16x8 a[4];
#pragma unroll
        for (int mt = 0; mt < 4; ++mt) {
            int r = wm * 64 + mt * 16 + lr;
            a[mt] = *(const bf16x8*)&ht[r * 128 + SWZ(r, c) * 8];
        }
#pragma unroll
        for (int nt = 0; nt < 4; ++nt) {
            int r = wn * 64 + nt * 16 + lr;
            bf16x8 b = *(const bf16x8*)&w2s[r * 128 + SWZ(r, c) * 8];
#pragma unroll
            for (int mt = 0; mt < 4; ++mt)
                acc2[mt][nt] = __builtin_amdgcn_mfma_f32_16x16x32_bf16(a[mt], b, acc2[mt][nt], 0, 0, 0);
        }
    }

#pragma unroll
    for (int nt = 0; nt < 4; ++nt) {
        int col = wn * 64 + nt * 16 + lr;
        float bv = b2[col];
#pragma unroll
        for (int mt = 0; mt < 4; ++mt)
#pragma unroll
            for (int q = 0; q < 4; ++q) {
                int gr = row0 + wm * 64 + mt * 16 + lk * 4 + q;
                if (gr < rows) {
                    int node = list ? list[gr] : gr;
                    float ov = fmaxf(acc2[mt][nt][q] + bv, 0.f);
                    *(__bf16*)&out[(size_t)node * 128 + col] = (__bf16)ov;
                }
            }
    }
}

// ---------------- layer 2 at roots only ----------------
__global__ __launch_bounds__(128) void k_root(const unsigned short* __restrict__ x2,
                                              const int* __restrict__ rp,
                                              const int* __restrict__ csr,
                                              const int* __restrict__ roots,
                                              const float* __restrict__ epsp,
                                              const float* __restrict__ wa,
                                              const float* __restrict__ ba,
                                              const float* __restrict__ wb,
                                              const float* __restrict__ bb,
                                              float* __restrict__ out) {
    __shared__ float hin[128];
    __shared__ float h[64];
    int r = blockIdx.x, t = threadIdx.x;
    int node = roots[r];
    float s = (1.0f + epsp[0]) * (float)(*(const __bf16*)&x2[(size_t)node * 128 + t]);
    int b = rp[node], e = rp[node + 1];
    for (int k = b; k < e; ++k)
        s += (float)(*(const __bf16*)&x2[(size_t)csr[k] * 128 + t]);
    hin[t] = s;
    __syncthreads();
    if (t < 64) {
        float a = ba[t];
        for (int k = 0; k < 128; ++k) a += hin[k] * wa[k * 64 + t];
        h[t] = fmaxf(a, 0.f);
    }
    __syncthreads();
    if (t < 64) {
        float a = bb[t];
        for (int k = 0; k < 64; ++k) a += h[k] * wb[k * 64 + t];
        out[(size_t)r * 64 + t] = a;
    }
}

extern "C" void kernel_launch(void* const* d_in, const int* in_sizes, int n_in,
                              void* d_out, int out_size, void* d_ws, size_t ws_size,
                              hipStream_t stream) {
    const float* x    = (const float*)d_in[0];
    const int*   ei   = (const int*)d_in[1];
    const int*   root = (const int*)d_in[2];
    const float* eps0 = (const float*)d_in[3];
    const float* w0a  = (const float*)d_in[4];
    const float* b0a  = (const float*)d_in[5];
    const float* w0b  = (const float*)d_in[6];
    const float* b0b  = (const float*)d_in[7];
    const float* eps1 = (const float*)d_in[8];
    const float* w1a  = (const float*)d_in[9];
    const float* b1a  = (const float*)d_in[10];
    const float* w1b  = (const float*)d_in[11];
    const float* b1b  = (const float*)d_in[12];
    const float* eps2 = (const float*)d_in[13];
    const float* w2a  = (const float*)d_in[14];
    const float* b2a  = (const float*)d_in[15];
    const float* w2b  = (const float*)d_in[16];
    const float* b2b  = (const float*)d_in[17];

    const int N  = in_sizes[0] / 128;
    const int E  = in_sizes[1] / 2;
    const int NR = in_sizes[2];
    const int MAXACT = 65536;
    const int NB = (N + 127) / 128;           // buckets of 128 nodes (782)
    const int* src = ei;
    const int* dst = ei + E;

    // ---- workspace layout ----
    char* p = (char*)d_ws;
    unsigned short* xb = (unsigned short*)p; p += (size_t)N * 128 * 2;        // 25.6 MB
    unsigned short* x1 = (unsigned short*)p; p += (size_t)N * 128 * 2;        // 25.6 MB
    // shared region: ebuf (CSR build) then ag0/x2 (layers) — disjoint in time
    char* shared0 = p;
    size_t ebuf_bytes = (size_t)NB * CAP * 4;                                 // 12.8 MB
    size_t ag0_bytes  = (size_t)N * 128 * 2;                                  // 25.6 MB
    p += (ebuf_bytes > ag0_bytes ? ebuf_bytes : ag0_bytes);
    unsigned*       ebuf = (unsigned*)shared0;
    unsigned short* ag0  = (unsigned short*)shared0;
    unsigned short* ag1  = (unsigned short*)p; p += (size_t)MAXACT * 128 * 2; // 16.8 MB
    unsigned short* w0aT = (unsigned short*)p; p += 128 * 128 * 2;
    unsigned short* w0bT = (unsigned short*)p; p += 128 * 128 * 2;
    unsigned short* w1aT = (unsigned short*)p; p += 128 * 128 * 2;
    unsigned short* w1bT = (unsigned short*)p; p += 128 * 128 * 2;
    int* rp   = (int*)p; p += (size_t)(N + 64) * 4;
    int* af   = (int*)p; p += (size_t)(N + 64) * 4;
    int* list = (int*)p; p += (size_t)(N + 64) * 4;
    int* cnt  = (int*)p; p += 256;
    int* boff = (int*)p; p += 4096;
    int* gcnt = (int*)p; p += (size_t)NB * 16 * 4;                            // 64B-padded
    int* csr  = (int*)p; p += (size_t)E * 4;
    unsigned short* x2 = ag0;   // reuse after mlp0

    // ---- conversions ----
    k_cvt_x<<<(N * 128 / 8 + 255) / 256, 256, 0, stream>>>((const float4*)x, xb, (long)N * 16);
    k_cvt_w<<<64, 256, 0, stream>>>(w0a, w0aT);
    k_cvt_w<<<64, 256, 0, stream>>>(w0b, w0bT);
    k_cvt_w<<<64, 256, 0, stream>>>(w1a, w1aT);
    k_cvt_w<<<64, 256, 0, stream>>>(w1b, w1bT);

    // ---- bucketed CSR build ----
    hipMemsetAsync(gcnt, 0, (size_t)NB * 16 * 4, stream);
    hipMemsetAsync(af,  0, (size_t)N * 4, stream);
    hipMemsetAsync(cnt, 0, 256, stream);
    k_scatter<<<SCAT_BLK, 256, 0, stream>>>(src, dst, gcnt, ebuf, E, NB);
    k_bscan<<<1, 1024, 0, stream>>>(gcnt, boff, rp, NB, N, E);
    k_build<<<NB, 256, 0, stream>>>(ebuf, gcnt, boff, rp, csr, N);

    // ---- active set ----
    k_flag<<<(NR + 255) / 256, 256, 0, stream>>>(root, NR, rp, csr, af);
    k_compact<<<(N + 255) / 256, 256, 0, stream>>>(af, list, cnt, N);

    // ---- layer 0 (all nodes) ----
    k_segsum<<<(N * 16 + 255) / 256, 256, 0, stream>>>(xb, rp, csr, ag0, nullptr, nullptr, N);
    k_mlp<<<(N + 127) / 128, 256, 0, stream>>>(xb, ag0, eps0, w0aT, b0a, w0bT, b0b,
                                               x1, nullptr, nullptr, N);
    // ---- layer 1 (active set only) ----
    k_segsum<<<(MAXACT * 16 + 255) / 256, 256, 0, stream>>>(x1, rp, csr, ag1, list, cnt, MAXACT);
    k_mlp<<<(MAXACT + 127) / 128, 256, 0, stream>>>(x1, ag1, eps1, w1aT, b1a, w1bT, b1b,
                                                    x2, list, cnt, MAXACT);
    // ---- layer 2 (roots only) ----
    k_root<<<NR, 128, 0, stream>>>(x2, rp, csr, root, eps2, w2a, b2a, w2b, b2b,
                                   (float*)d_out);
}

// Round 6
// 326.358 us; speedup vs baseline: 1.2825x; 1.2825x over previous
//
#include <hip/hip_runtime.h>

// ---------------------------------------------------------------------------
// GIN 3-layer forward on MI355X (gfx950).
//   - features/weights quantized to bf16 once per call (f32 accumulate)
//   - CSR built via dst-bucketing:
//       k_scatter: per-edge atomic append into (bucket, XCD) cells.
//                  sub-cell = blockIdx&7 (XCD id) so each cell's frontier
//                  64B line is written by ONE XCD -> stays L2-resident ->
//                  no partial-line write amplification (R4: 83MB, R5 LDS
//                  variant: occupancy collapse; this: best of both)
//       k_bscan:   exclusive scan of bucket totals
//       k_build:   per-bucket LDS histogram + scan -> rp, slotting -> csr
//   - segment-sum gather: 16 lanes/node, bf16x8 loads, f32 accum
//   - MLP: MFMA 16x16x32 bf16, BM=128 block, 4 waves (2x2 of 64x64),
//     128 KB LDS, XOR-swizzled
//   - layer 1 only on active set = roots U in-neighbors(roots)
//   - layer 2 only at the 1024 roots
//   NOTE: edge packing assumes N <= 2^17 (src in 17 bits, local dst in 7).
// ---------------------------------------------------------------------------

typedef __bf16  bf16x8 __attribute__((ext_vector_type(8)));
typedef float   f32x4  __attribute__((ext_vector_type(4)));

#define SWZ(r, c) ((c) ^ ((r) & 7))   // c = 16B-chunk index within a 256B row

#define CELL_CAP  1024                // slots per (bucket,xcd) cell; mean ~256
#define SUBS      8                   // one sub-cell per XCD

// ---------------- conversion kernels ----------------
__global__ __launch_bounds__(256) void k_cvt_x(const float4* __restrict__ in,
                                               unsigned short* __restrict__ outb,
                                               long n8) {
    long i = (long)blockIdx.x * 256 + threadIdx.x;
    if (i >= n8) return;
    float4 a = in[2 * i], b = in[2 * i + 1];
    bf16x8 v;
    v[0] = (__bf16)a.x; v[1] = (__bf16)a.y; v[2] = (__bf16)a.z; v[3] = (__bf16)a.w;
    v[4] = (__bf16)b.x; v[5] = (__bf16)b.y; v[6] = (__bf16)b.z; v[7] = (__bf16)b.w;
    *(bf16x8*)&outb[i * 8] = v;
}

// wT[n][k] = (bf16) w[k][n]   (128x128)
__global__ __launch_bounds__(256) void k_cvt_w(const float* __restrict__ w,
                                               unsigned short* __restrict__ wT) {
    int i = blockIdx.x * 256 + threadIdx.x;   // 16384
    int k = i >> 7, n = i & 127;
    *(__bf16*)&wT[n * 128 + k] = (__bf16)w[i];
}

// ---------------- bucketed CSR build ----------------
// scatter edges into (bucket = dst>>7, xcd) cells; packed = ldst<<17 | src
__global__ __launch_bounds__(256) void k_scatter(const int* __restrict__ src,
                                                 const int* __restrict__ dst,
                                                 int* __restrict__ bcnt,
                                                 unsigned* __restrict__ ebuf, int e) {
    int i = blockIdx.x * 256 + threadIdx.x;
    if (i >= e) return;
    int d = dst[i];
    int s = src[i];
    int cell = (d >> 7) * SUBS + (blockIdx.x & (SUBS - 1));  // sub = XCD id
    int p = atomicAdd(&bcnt[cell * 16], 1);        // 16-int pad: 1 counter/line
    if (p < CELL_CAP)
        ebuf[((size_t)cell << 10) + p] = (unsigned)s | ((unsigned)(d & 127) << 17);
}

// one block: exclusive scan of nb bucket totals (nb <= 1024); also rp[n]=e
__global__ __launch_bounds__(1024) void k_bscan(const int* __restrict__ bcnt,
                                                int* __restrict__ boff,
                                                int* __restrict__ rp,
                                                int nb, int n, int e) {
    __shared__ int sh[1024];
    int t = threadIdx.x;
    int s = 0;
    if (t < nb)
#pragma unroll
        for (int q = 0; q < SUBS; ++q) {
            int c = bcnt[(t * SUBS + q) * 16];
            s += (c < CELL_CAP ? c : CELL_CAP);
        }
    sh[t] = s;
    __syncthreads();
    for (int off = 1; off < 1024; off <<= 1) {
        int u = (t >= off) ? sh[t - off] : 0;
        __syncthreads();
        sh[t] += u;
        __syncthreads();
    }
    if (t < nb) boff[t] = (t == 0) ? 0 : sh[t - 1];
    if (t == 0) rp[n] = e;
}

// one block per bucket: LDS histogram -> scan -> rp write -> csr slotting
__global__ __launch_bounds__(256) void k_build(const unsigned* __restrict__ ebuf,
                                               const int* __restrict__ bcnt,
                                               const int* __restrict__ boff,
                                               int* __restrict__ rp,
                                               int* __restrict__ csr, int n) {
    __shared__ int bins[128];
    __shared__ int incl[128];
    __shared__ int cur[128];
    __shared__ int scnt[SUBS];
    int b = blockIdx.x, t = threadIdx.x;
    if (t < 128) bins[t] = 0;
    if (t < SUBS) {
        int c = bcnt[(b * SUBS + t) * 16];
        scnt[t] = c < CELL_CAP ? c : CELL_CAP;
    }
    __syncthreads();
    // histogram of local dst
    for (int s = 0; s < SUBS; ++s) {
        int c = scnt[s];
        const unsigned* seg = ebuf + (((size_t)(b * SUBS + s)) << 10);
        for (int j = t; j < c; j += 256)
            atomicAdd(&bins[(seg[j] >> 17) & 127], 1);
    }
    __syncthreads();
    if (t < 128) incl[t] = bins[t];
    __syncthreads();
    for (int off = 1; off < 128; off <<= 1) {
        int u = (t < 128 && t >= off) ? incl[t - off] : 0;
        __syncthreads();
        if (t < 128) incl[t] += u;
        __syncthreads();
    }
    int base = boff[b];
    if (t < 128) {
        int ex = (t == 0) ? 0 : incl[t - 1];
        cur[t] = ex;
        int node = b * 128 + t;
        if (node < n) rp[node] = base + ex;
    }
    __syncthreads();
    // slot and write csr (contiguous ~8KB window per block)
    for (int s = 0; s < SUBS; ++s) {
        int c = scnt[s];
        const unsigned* seg = ebuf + (((size_t)(b * SUBS + s)) << 10);
        for (int j = t; j < c; j += 256) {
            unsigned w = seg[j];
            int slot = atomicAdd(&cur[(w >> 17) & 127], 1);
            csr[base + slot] = (int)(w & 0x1FFFF);
        }
    }
}

// ---------------- active set (roots + their in-neighbors) ----------------
__global__ void k_flag(const int* __restrict__ roots, int nr,
                       const int* __restrict__ rp, const int* __restrict__ csr,
                       int* __restrict__ af) {
    int i = blockIdx.x * blockDim.x + threadIdx.x;
    if (i >= nr) return;
    int r = roots[i];
    af[r] = 1;
    int e = rp[r + 1];
    for (int k = rp[r]; k < e; ++k) af[csr[k]] = 1;
}

__global__ void k_compact(const int* __restrict__ af, int* __restrict__ list,
                          int* __restrict__ cnt, int n) {
    int i = blockIdx.x * blockDim.x + threadIdx.x;
    if (i < n && af[i]) {
        int p = atomicAdd(cnt, 1);
        list[p] = i;
    }
}

// ---------------- segment sum (bf16 in, bf16 out, f32 accumulate) ----------
__global__ __launch_bounds__(256) void k_segsum(const unsigned short* __restrict__ xb,
                                                const int* __restrict__ rp,
                                                const int* __restrict__ csr,
                                                unsigned short* __restrict__ agg,
                                                const int* __restrict__ list,
                                                const int* __restrict__ cntp, int n) {
    int gid = blockIdx.x * 256 + threadIdx.x;
    int j = gid >> 4, lane = gid & 15;
    int rows = n;
    if (cntp) { int c = *cntp; rows = c < n ? c : n; }
    if (j >= rows) return;
    int node = list ? list[j] : j;
    int b = rp[node], e = rp[node + 1];
    float s0[8], s1[8];
#pragma unroll
    for (int q = 0; q < 8; ++q) { s0[q] = 0.f; s1[q] = 0.f; }
    int k = b;
    for (; k + 1 < e; k += 2) {
        bf16x8 v0 = *(const bf16x8*)&xb[(size_t)csr[k]     * 128 + lane * 8];
        bf16x8 v1 = *(const bf16x8*)&xb[(size_t)csr[k + 1] * 128 + lane * 8];
#pragma unroll
        for (int q = 0; q < 8; ++q) { s0[q] += (float)v0[q]; s1[q] += (float)v1[q]; }
    }
    if (k < e) {
        bf16x8 v0 = *(const bf16x8*)&xb[(size_t)csr[k] * 128 + lane * 8];
#pragma unroll
        for (int q = 0; q < 8; ++q) s0[q] += (float)v0[q];
    }
    bf16x8 o;
#pragma unroll
    for (int q = 0; q < 8; ++q) o[q] = (__bf16)(s0[q] + s1[q]);
    *(bf16x8*)&agg[(size_t)j * 128 + lane * 8] = o;
}

// ---------------- fused MLP: relu( relu(z@w1+b1) @ w2 + b2 ), z=(1+eps)x+agg
__global__ __launch_bounds__(256) void k_mlp(const unsigned short* __restrict__ xb,
                                             const unsigned short* __restrict__ aggb,
                                             const float* __restrict__ epsp,
                                             const unsigned short* __restrict__ w1T,
                                             const float* __restrict__ b1,
                                             const unsigned short* __restrict__ w2T,
                                             const float* __restrict__ b2,
                                             unsigned short* __restrict__ out,
                                             const int* __restrict__ list,
                                             const int* __restrict__ cntp, int nrows) {
    __shared__ unsigned short zt [128 * 128];
    __shared__ unsigned short ht [128 * 128];
    __shared__ unsigned short w1s[128 * 128];
    __shared__ unsigned short w2s[128 * 128];
    const int t = threadIdx.x;
    int rows = nrows;
    if (cntp) { int c = *cntp; rows = c < nrows ? c : nrows; }
    const int row0 = blockIdx.x * 128;
    if (row0 >= rows) return;
    const float epsv = 1.0f + epsp[0];

    for (int i = t; i < 2048; i += 256) {
        int r = i >> 4, c = i & 15;
        int d = r * 128 + SWZ(r, c) * 8;
        *(f32x4*)&w1s[d] = *(const f32x4*)&w1T[i * 8];
        *(f32x4*)&w2s[d] = *(const f32x4*)&w2T[i * 8];
    }
    for (int i = t; i < 2048; i += 256) {
        int r = i >> 4, c = i & 15;
        int g = row0 + r;
        bf16x8 zv;
        if (g < rows) {
            int node = list ? list[g] : g;
            bf16x8 xv = *(const bf16x8*)&xb  [(size_t)node * 128 + c * 8];
            bf16x8 av = *(const bf16x8*)&aggb[(size_t)g    * 128 + c * 8];
#pragma unroll
            for (int q = 0; q < 8; ++q)
                zv[q] = (__bf16)(epsv * (float)xv[q] + (float)av[q]);
        } else {
#pragma unroll
            for (int q = 0; q < 8; ++q) zv[q] = (__bf16)0.0f;
        }
        *(bf16x8*)&zt[r * 128 + SWZ(r, c) * 8] = zv;
    }
    __syncthreads();

    const int lane = t & 63;
    const int wm = (t >> 7) & 1, wn = (t >> 6) & 1;
    const int lr = lane & 15, lk = lane >> 4;

    f32x4 zero4 = {0.f, 0.f, 0.f, 0.f};
    f32x4 acc[4][4];
#pragma unroll
    for (int mt = 0; mt < 4; ++mt)
#pragma unroll
        for (int nt = 0; nt < 4; ++nt) acc[mt][nt] = zero4;

#pragma unroll
    for (int kb = 0; kb < 4; ++kb) {
        const int c = kb * 4 + lk;
        bf16x8 a[4];
#pragma unroll
        for (int mt = 0; mt < 4; ++mt) {
            int r = wm * 64 + mt * 16 + lr;
            a[mt] = *(const bf16x8*)&zt[r * 128 + SWZ(r, c) * 8];
        }
#pragma unroll
        for (int nt = 0; nt < 4; ++nt) {
            int r = wn * 64 + nt * 16 + lr;
            bf16x8 b = *(const bf16x8*)&w1s[r * 128 + SWZ(r, c) * 8];
#pragma unroll
            for (int mt = 0; mt < 4; ++mt)
                acc[mt][nt] = __builtin_amdgcn_mfma_f32_16x16x32_bf16(a[mt], b, acc[mt][nt], 0, 0, 0);
        }
    }

#pragma unroll
    for (int nt = 0; nt < 4; ++nt) {
        int col = wn * 64 + nt * 16 + lr;
        float bv = b1[col];
        int c8 = col >> 3, ci = col & 7;
#pragma unroll
        for (int mt = 0; mt < 4; ++mt)
#pragma unroll
            for (int q = 0; q < 4; ++q) {
                int hr = wm * 64 + mt * 16 + lk * 4 + q;
                float hv = fmaxf(acc[mt][nt][q] + bv, 0.f);
                *(__bf16*)&ht[hr * 128 + SWZ(hr, c8) * 8 + ci] = (__bf16)hv;
            }
    }
    __syncthreads();

    f32x4 acc2[4][4];
#pragma unroll
    for (int mt = 0; mt < 4; ++mt)
#pragma unroll
        for (int nt = 0; nt < 4; ++nt) acc2[mt][nt] = zero4;
#pragma unroll
    for (int kb = 0; kb < 4; ++kb) {
        const int c = kb * 4 + lk;
        bf16x8 a[4];
#pragma unroll
        for (int mt = 0; mt < 4; ++mt) {
            int r = wm * 64 + mt * 16 + lr;
            a[mt] = *(const bf16x8*)&ht[r * 128 + SWZ(r, c) * 8];
        }
#pragma unroll
        for (int nt = 0; nt < 4; ++nt) {
            int r = wn * 64 + nt * 16 + lr;
            bf16x8 b = *(const bf16x8*)&w2s[r * 128 + SWZ(r, c) * 8];
#pragma unroll
            for (int mt = 0; mt < 4; ++mt)
                acc2[mt][nt] = __builtin_amdgcn_mfma_f32_16x16x32_bf16(a[mt], b, acc2[mt][nt], 0, 0, 0);
        }
    }

#pragma unroll
    for (int nt = 0; nt < 4; ++nt) {
        int col = wn * 64 + nt * 16 + lr;
        float bv = b2[col];
#pragma unroll
        for (int mt = 0; mt < 4; ++mt)
#pragma unroll
            for (int q = 0; q < 4; ++q) {
                int gr = row0 + wm * 64 + mt * 16 + lk * 4 + q;
                if (gr < rows) {
                    int node = list ? list[gr] : gr;
                    float ov = fmaxf(acc2[mt][nt][q] + bv, 0.f);
                    *(__bf16*)&out[(size_t)node * 128 + col] = (__bf16)ov;
                }
            }
    }
}

// ---------------- layer 2 at roots only ----------------
__global__ __launch_bounds__(128) void k_root(const unsigned short* __restrict__ x2,
                                              const int* __restrict__ rp,
                                              const int* __restrict__ csr,
                                              const int* __restrict__ roots,
                                              const float* __restrict__ epsp,
                                              const float* __restrict__ wa,
                                              const float* __restrict__ ba,
                                              const float* __restrict__ wb,
                                              const float* __restrict__ bb,
                                              float* __restrict__ out) {
    __shared__ float hin[128];
    __shared__ float h[64];
    int r = blockIdx.x, t = threadIdx.x;
    int node = roots[r];
    float s = (1.0f + epsp[0]) * (float)(*(const __bf16*)&x2[(size_t)node * 128 + t]);
    int b = rp[node], e = rp[node + 1];
    for (int k = b; k < e; ++k)
        s += (float)(*(const __bf16*)&x2[(size_t)csr[k] * 128 + t]);
    hin[t] = s;
    __syncthreads();
    if (t < 64) {
        float a = ba[t];
        for (int k = 0; k < 128; ++k) a += hin[k] * wa[k * 64 + t];
        h[t] = fmaxf(a, 0.f);
    }
    __syncthreads();
    if (t < 64) {
        float a = bb[t];
        for (int k = 0; k < 64; ++k) a += h[k] * wb[k * 64 + t];
        out[(size_t)r * 64 + t] = a;
    }
}

extern "C" void kernel_launch(void* const* d_in, const int* in_sizes, int n_in,
                              void* d_out, int out_size, void* d_ws, size_t ws_size,
                              hipStream_t stream) {
    const float* x    = (const float*)d_in[0];
    const int*   ei   = (const int*)d_in[1];
    const int*   root = (const int*)d_in[2];
    const float* eps0 = (const float*)d_in[3];
    const float* w0a  = (const float*)d_in[4];
    const float* b0a  = (const float*)d_in[5];
    const float* w0b  = (const float*)d_in[6];
    const float* b0b  = (const float*)d_in[7];
    const float* eps1 = (const float*)d_in[8];
    const float* w1a  = (const float*)d_in[9];
    const float* b1a  = (const float*)d_in[10];
    const float* w1b  = (const float*)d_in[11];
    const float* b1b  = (const float*)d_in[12];
    const float* eps2 = (const float*)d_in[13];
    const float* w2a  = (const float*)d_in[14];
    const float* b2a  = (const float*)d_in[15];
    const float* w2b  = (const float*)d_in[16];
    const float* b2b  = (const float*)d_in[17];

    const int N  = in_sizes[0] / 128;
    const int E  = in_sizes[1] / 2;
    const int NR = in_sizes[2];
    const int MAXACT = 65536;
    const int NB = (N + 127) / 128;           // buckets of 128 nodes (782)
    const int* src = ei;
    const int* dst = ei + E;

    // ---- workspace layout ----
    char* p = (char*)d_ws;
    unsigned short* xb = (unsigned short*)p; p += (size_t)N * 128 * 2;        // 25.6 MB
    unsigned short* x1 = (unsigned short*)p; p += (size_t)N * 128 * 2;        // 25.6 MB
    // shared region: ebuf (CSR build) then ag0/x2 (layers) — disjoint in time
    char* shared0 = p;
    size_t ebuf_bytes = (size_t)NB * SUBS * CELL_CAP * 4;                     // 25.6 MB
    size_t ag0_bytes  = (size_t)N * 128 * 2;                                  // 25.6 MB
    p += (ebuf_bytes > ag0_bytes ? ebuf_bytes : ag0_bytes);
    unsigned*       ebuf = (unsigned*)shared0;
    unsigned short* ag0  = (unsigned short*)shared0;
    unsigned short* ag1  = (unsigned short*)p; p += (size_t)MAXACT * 128 * 2; // 16.8 MB
    unsigned short* w0aT = (unsigned short*)p; p += 128 * 128 * 2;
    unsigned short* w0bT = (unsigned short*)p; p += 128 * 128 * 2;
    unsigned short* w1aT = (unsigned short*)p; p += 128 * 128 * 2;
    unsigned short* w1bT = (unsigned short*)p; p += 128 * 128 * 2;
    int* rp   = (int*)p; p += (size_t)(N + 64) * 4;
    int* af   = (int*)p; p += (size_t)(N + 64) * 4;
    int* list = (int*)p; p += (size_t)(N + 64) * 4;
    int* cnt  = (int*)p; p += 256;
    int* boff = (int*)p; p += 4096;
    int* bcnt = (int*)p; p += (size_t)NB * SUBS * 16 * 4;                     // padded counters
    int* csr  = (int*)p; p += (size_t)E * 4;
    unsigned short* x2 = ag0;   // reuse after mlp0

    // ---- conversions ----
    k_cvt_x<<<(N * 128 / 8 + 255) / 256, 256, 0, stream>>>((const float4*)x, xb, (long)N * 16);
    k_cvt_w<<<64, 256, 0, stream>>>(w0a, w0aT);
    k_cvt_w<<<64, 256, 0, stream>>>(w0b, w0bT);
    k_cvt_w<<<64, 256, 0, stream>>>(w1a, w1aT);
    k_cvt_w<<<64, 256, 0, stream>>>(w1b, w1bT);

    // ---- bucketed CSR build ----
    hipMemsetAsync(bcnt, 0, (size_t)NB * SUBS * 16 * 4, stream);
    hipMemsetAsync(af,  0, (size_t)N * 4, stream);
    hipMemsetAsync(cnt, 0, 256, stream);
    k_scatter<<<(E + 255) / 256, 256, 0, stream>>>(src, dst, bcnt, ebuf, E);
    k_bscan<<<1, 1024, 0, stream>>>(bcnt, boff, rp, NB, N, E);
    k_build<<<NB, 256, 0, stream>>>(ebuf, bcnt, boff, rp, csr, N);

    // ---- active set ----
    k_flag<<<(NR + 255) / 256, 256, 0, stream>>>(root, NR, rp, csr, af);
    k_compact<<<(N + 255) / 256, 256, 0, stream>>>(af, list, cnt, N);

    // ---- layer 0 (all nodes) ----
    k_segsum<<<(N * 16 + 255) / 256, 256, 0, stream>>>(xb, rp, csr, ag0, nullptr, nullptr, N);
    k_mlp<<<(N + 127) / 128, 256, 0, stream>>>(xb, ag0, eps0, w0aT, b0a, w0bT, b0b,
                                               x1, nullptr, nullptr, N);
    // ---- layer 1 (active set only) ----
    k_segsum<<<(MAXACT * 16 + 255) / 256, 256, 0, stream>>>(x1, rp, csr, ag1, list, cnt, MAXACT);
    k_mlp<<<(MAXACT + 127) / 128, 256, 0, stream>>>(x1, ag1, eps1, w1aT, b1a, w1bT, b1b,
                                                    x2, list, cnt, MAXACT);
    // ---- layer 2 (roots only) ----
    k_root<<<NR, 128, 0, stream>>>(x2, rp, csr, root, eps2, w2a, b2a, w2b, b2b,
                                   (float*)d_out);
}

// Round 7
// 294.359 us; speedup vs baseline: 1.4219x; 1.1087x over previous
//
#include <hip/hip_runtime.h>

// ---------------------------------------------------------------------------
// GIN 3-layer forward on MI355X (gfx950).
//   - features/weights quantized to bf16 once per call (f32 accumulate)
//   - CSR built via dst-bucketing; scatter sub-cell = blockIdx&7 (XCD id)
//     so each cell's frontier 64B line is written by ONE XCD (L2-resident)
//   - segment-sum gather: 16 lanes/node, bf16x8 loads, f32 accum
//   - MLP: MFMA 16x16x32 bf16, BM=128, 4 waves (2x2 of 64x64), 64KB LDS:
//       zt (z, then h in-place) + wbuf (w1, then w2), rows padded to 136
//       shorts (272B) -> all LDS access classes <=2-way (free), no swizzle
//   - layer 1 only on active set = roots U in-neighbors(roots)
//   - layer 2 only at the 1024 roots
//   NOTE: edge packing assumes N <= 2^17 (src in 17 bits, local dst in 7).
// ---------------------------------------------------------------------------

typedef __bf16  bf16x8 __attribute__((ext_vector_type(8)));
typedef float   f32x4  __attribute__((ext_vector_type(4)));

#define CELL_CAP  1024                // slots per (bucket,xcd) cell; mean ~256
#define SUBS      8                   // one sub-cell per XCD
#define LDR       136                 // LDS row stride in shorts (+8 pad)

// ---------------- conversion kernels ----------------
__global__ __launch_bounds__(256) void k_cvt_x(const float4* __restrict__ in,
                                               unsigned short* __restrict__ outb,
                                               long n8) {
    long i = (long)blockIdx.x * 256 + threadIdx.x;
    if (i >= n8) return;
    float4 a = in[2 * i], b = in[2 * i + 1];
    bf16x8 v;
    v[0] = (__bf16)a.x; v[1] = (__bf16)a.y; v[2] = (__bf16)a.z; v[3] = (__bf16)a.w;
    v[4] = (__bf16)b.x; v[5] = (__bf16)b.y; v[6] = (__bf16)b.z; v[7] = (__bf16)b.w;
    *(bf16x8*)&outb[i * 8] = v;
}

// 4 weight matrices -> transposed bf16, contiguous output (4 x 128 x 128)
__global__ __launch_bounds__(256) void k_cvt_w4(const float* __restrict__ wa,
                                                const float* __restrict__ wb,
                                                const float* __restrict__ wc,
                                                const float* __restrict__ wd,
                                                unsigned short* __restrict__ out) {
    int i = blockIdx.x * 256 + threadIdx.x;    // 65536
    int m = i >> 14, j = i & 16383;
    const float* w = (m == 0) ? wa : (m == 1) ? wb : (m == 2) ? wc : wd;
    int k = j >> 7, n = j & 127;
    *(__bf16*)&out[m * 16384 + n * 128 + k] = (__bf16)w[j];
}

// ---------------- bucketed CSR build ----------------
// scatter edges into (bucket = dst>>7, xcd) cells; packed = ldst<<17 | src
__global__ __launch_bounds__(256) void k_scatter(const int* __restrict__ src,
                                                 const int* __restrict__ dst,
                                                 int* __restrict__ bcnt,
                                                 unsigned* __restrict__ ebuf, int e) {
    int i = blockIdx.x * 256 + threadIdx.x;
    if (i >= e) return;
    int d = dst[i];
    int s = src[i];
    int cell = (d >> 7) * SUBS + (blockIdx.x & (SUBS - 1));  // sub = XCD id
    int p = atomicAdd(&bcnt[cell * 16], 1);        // 16-int pad: 1 counter/line
    if (p < CELL_CAP)
        ebuf[((size_t)cell << 10) + p] = (unsigned)s | ((unsigned)(d & 127) << 17);
}

// one block: exclusive scan of nb bucket totals (nb <= 1024); also rp[n]=e
__global__ __launch_bounds__(1024) void k_bscan(const int* __restrict__ bcnt,
                                                int* __restrict__ boff,
                                                int* __restrict__ rp,
                                                int nb, int n, int e) {
    __shared__ int sh[1024];
    int t = threadIdx.x;
    int s = 0;
    if (t < nb)
#pragma unroll
        for (int q = 0; q < SUBS; ++q) {
            int c = bcnt[(t * SUBS + q) * 16];
            s += (c < CELL_CAP ? c : CELL_CAP);
        }
    sh[t] = s;
    __syncthreads();
    for (int off = 1; off < 1024; off <<= 1) {
        int u = (t >= off) ? sh[t - off] : 0;
        __syncthreads();
        sh[t] += u;
        __syncthreads();
    }
    if (t < nb) boff[t] = (t == 0) ? 0 : sh[t - 1];
    if (t == 0) rp[n] = e;
}

// one block per bucket: LDS histogram -> scan -> rp write -> csr slotting
__global__ __launch_bounds__(256) void k_build(const unsigned* __restrict__ ebuf,
                                               const int* __restrict__ bcnt,
                                               const int* __restrict__ boff,
                                               int* __restrict__ rp,
                                               int* __restrict__ csr, int n) {
    __shared__ int bins[128];
    __shared__ int incl[128];
    __shared__ int cur[128];
    __shared__ int scnt[SUBS];
    int b = blockIdx.x, t = threadIdx.x;
    if (t < 128) bins[t] = 0;
    if (t < SUBS) {
        int c = bcnt[(b * SUBS + t) * 16];
        scnt[t] = c < CELL_CAP ? c : CELL_CAP;
    }
    __syncthreads();
    for (int s = 0; s < SUBS; ++s) {
        int c = scnt[s];
        const unsigned* seg = ebuf + (((size_t)(b * SUBS + s)) << 10);
        for (int j = t; j < c; j += 256)
            atomicAdd(&bins[(seg[j] >> 17) & 127], 1);
    }
    __syncthreads();
    if (t < 128) incl[t] = bins[t];
    __syncthreads();
    for (int off = 1; off < 128; off <<= 1) {
        int u = (t < 128 && t >= off) ? incl[t - off] : 0;
        __syncthreads();
        if (t < 128) incl[t] += u;
        __syncthreads();
    }
    int base = boff[b];
    if (t < 128) {
        int ex = (t == 0) ? 0 : incl[t - 1];
        cur[t] = ex;
        int node = b * 128 + t;
        if (node < n) rp[node] = base + ex;
    }
    __syncthreads();
    for (int s = 0; s < SUBS; ++s) {
        int c = scnt[s];
        const unsigned* seg = ebuf + (((size_t)(b * SUBS + s)) << 10);
        for (int j = t; j < c; j += 256) {
            unsigned w = seg[j];
            int slot = atomicAdd(&cur[(w >> 17) & 127], 1);
            csr[base + slot] = (int)(w & 0x1FFFF);
        }
    }
}

// ---------------- active set (roots + their in-neighbors) ----------------
__global__ void k_flag(const int* __restrict__ roots, int nr,
                       const int* __restrict__ rp, const int* __restrict__ csr,
                       int* __restrict__ af) {
    int i = blockIdx.x * blockDim.x + threadIdx.x;
    if (i >= nr) return;
    int r = roots[i];
    af[r] = 1;
    int e = rp[r + 1];
    for (int k = rp[r]; k < e; ++k) af[csr[k]] = 1;
}

__global__ void k_compact(const int* __restrict__ af, int* __restrict__ list,
                          int* __restrict__ cnt, int n) {
    int i = blockIdx.x * blockDim.x + threadIdx.x;
    if (i < n && af[i]) {
        int p = atomicAdd(cnt, 1);
        list[p] = i;
    }
}

// ---------------- segment sum (bf16 in, bf16 out, f32 accumulate) ----------
__global__ __launch_bounds__(256) void k_segsum(const unsigned short* __restrict__ xb,
                                                const int* __restrict__ rp,
                                                const int* __restrict__ csr,
                                                unsigned short* __restrict__ agg,
                                                const int* __restrict__ list,
                                                const int* __restrict__ cntp, int n) {
    int gid = blockIdx.x * 256 + threadIdx.x;
    int j = gid >> 4, lane = gid & 15;
    int rows = n;
    if (cntp) { int c = *cntp; rows = c < n ? c : n; }
    if (j >= rows) return;
    int node = list ? list[j] : j;
    int b = rp[node], e = rp[node + 1];
    float s0[8], s1[8];
#pragma unroll
    for (int q = 0; q < 8; ++q) { s0[q] = 0.f; s1[q] = 0.f; }
    int k = b;
    for (; k + 1 < e; k += 2) {
        bf16x8 v0 = *(const bf16x8*)&xb[(size_t)csr[k]     * 128 + lane * 8];
        bf16x8 v1 = *(const bf16x8*)&xb[(size_t)csr[k + 1] * 128 + lane * 8];
#pragma unroll
        for (int q = 0; q < 8; ++q) { s0[q] += (float)v0[q]; s1[q] += (float)v1[q]; }
    }
    if (k < e) {
        bf16x8 v0 = *(const bf16x8*)&xb[(size_t)csr[k] * 128 + lane * 8];
#pragma unroll
        for (int q = 0; q < 8; ++q) s0[q] += (float)v0[q];
    }
    bf16x8 o;
#pragma unroll
    for (int q = 0; q < 8; ++q) o[q] = (__bf16)(s0[q] + s1[q]);
    *(bf16x8*)&agg[(size_t)j * 128 + lane * 8] = o;
}

// ---------------- fused MLP: relu( relu(z@w1+b1) @ w2 + b2 ), z=(1+eps)x+agg
// BM=128 rows/block, 256 threads = 4 waves in 2x2 over the 128x128 output.
// 64KB LDS (2 blocks/CU): zt holds z then h (in place); wbuf holds w1 then w2.
__global__ __launch_bounds__(256) void k_mlp(const unsigned short* __restrict__ xb,
                                             const unsigned short* __restrict__ aggb,
                                             const float* __restrict__ epsp,
                                             const unsigned short* __restrict__ w1T,
                                             const float* __restrict__ b1,
                                             const unsigned short* __restrict__ w2T,
                                             const float* __restrict__ b2,
                                             unsigned short* __restrict__ out,
                                             const int* __restrict__ list,
                                             const int* __restrict__ cntp, int nrows) {
    __shared__ unsigned short zt  [128 * LDR];   // 34.8 KB
    __shared__ unsigned short wbuf[128 * LDR];   // 34.8 KB
    const int t = threadIdx.x;
    int rows = nrows;
    if (cntp) { int c = *cntp; rows = c < nrows ? c : nrows; }
    const int row0 = blockIdx.x * 128;
    if (row0 >= rows) return;
    const float epsv = 1.0f + epsp[0];

    // stage w1 and z
    for (int i = t; i < 2048; i += 256) {
        int r = i >> 4, c = i & 15;
        *(bf16x8*)&wbuf[r * LDR + c * 8] = *(const bf16x8*)&w1T[i * 8];
    }
    for (int i = t; i < 2048; i += 256) {
        int r = i >> 4, c = i & 15;
        int g = row0 + r;
        bf16x8 zv;
        if (g < rows) {
            int node = list ? list[g] : g;
            bf16x8 xv = *(const bf16x8*)&xb  [(size_t)node * 128 + c * 8];
            bf16x8 av = *(const bf16x8*)&aggb[(size_t)g    * 128 + c * 8];
#pragma unroll
            for (int q = 0; q < 8; ++q)
                zv[q] = (__bf16)(epsv * (float)xv[q] + (float)av[q]);
        } else {
#pragma unroll
            for (int q = 0; q < 8; ++q) zv[q] = (__bf16)0.0f;
        }
        *(bf16x8*)&zt[r * LDR + c * 8] = zv;
    }
    __syncthreads();

    const int lane = t & 63;
    const int wm = (t >> 7) & 1, wn = (t >> 6) & 1;
    const int lr = lane & 15, lk = lane >> 4;

    f32x4 zero4 = {0.f, 0.f, 0.f, 0.f};
    f32x4 acc[4][4];
#pragma unroll
    for (int mt = 0; mt < 4; ++mt)
#pragma unroll
        for (int nt = 0; nt < 4; ++nt) acc[mt][nt] = zero4;

    // -------- GEMM1: z @ w1 --------
#pragma unroll
    for (int kb = 0; kb < 4; ++kb) {
        const int c = kb * 4 + lk;
        bf16x8 a[4];
#pragma unroll
        for (int mt = 0; mt < 4; ++mt)
            a[mt] = *(const bf16x8*)&zt[(wm * 64 + mt * 16 + lr) * LDR + c * 8];
#pragma unroll
        for (int nt = 0; nt < 4; ++nt) {
            bf16x8 b = *(const bf16x8*)&wbuf[(wn * 64 + nt * 16 + lr) * LDR + c * 8];
#pragma unroll
            for (int mt = 0; mt < 4; ++mt)
                acc[mt][nt] = __builtin_amdgcn_mfma_f32_16x16x32_bf16(a[mt], b, acc[mt][nt], 0, 0, 0);
        }
    }
    __syncthreads();   // all zt / wbuf reads done

    // h = relu(acc + b1) -> zt (in place); stage w2 -> wbuf
#pragma unroll
    for (int nt = 0; nt < 4; ++nt) {
        int col = wn * 64 + nt * 16 + lr;
        float bv = b1[col];
#pragma unroll
        for (int mt = 0; mt < 4; ++mt)
#pragma unroll
            for (int q = 0; q < 4; ++q) {
                int hr = wm * 64 + mt * 16 + lk * 4 + q;
                float hv = fmaxf(acc[mt][nt][q] + bv, 0.f);
                *(__bf16*)&zt[hr * LDR + col] = (__bf16)hv;
            }
    }
    for (int i = t; i < 2048; i += 256) {
        int r = i >> 4, c = i & 15;
        *(bf16x8*)&wbuf[r * LDR + c * 8] = *(const bf16x8*)&w2T[i * 8];
    }
    __syncthreads();

    // -------- GEMM2: h @ w2 --------
    f32x4 acc2[4][4];
#pragma unroll
    for (int mt = 0; mt < 4; ++mt)
#pragma unroll
        for (int nt = 0; nt < 4; ++nt) acc2[mt][nt] = zero4;
#pragma unroll
    for (int kb = 0; kb < 4; ++kb) {
        const int c = kb * 4 + lk;
        bf16x8 a[4];
#pragma unroll
        for (int mt = 0; mt < 4; ++mt)
            a[mt] = *(const bf16x8*)&zt[(wm * 64 + mt * 16 + lr) * LDR + c * 8];
#pragma unroll
        for (int nt = 0; nt < 4; ++nt) {
            bf16x8 b = *(const bf16x8*)&wbuf[(wn * 64 + nt * 16 + lr) * LDR + c * 8];
#pragma unroll
            for (int mt = 0; mt < 4; ++mt)
                acc2[mt][nt] = __builtin_amdgcn_mfma_f32_16x16x32_bf16(a[mt], b, acc2[mt][nt], 0, 0, 0);
        }
    }

    // out = relu(acc2 + b2), bf16 scalar global stores
#pragma unroll
    for (int nt = 0; nt < 4; ++nt) {
        int col = wn * 64 + nt * 16 + lr;
        float bv = b2[col];
#pragma unroll
        for (int mt = 0; mt < 4; ++mt)
#pragma unroll
            for (int q = 0; q < 4; ++q) {
                int gr = row0 + wm * 64 + mt * 16 + lk * 4 + q;
                if (gr < rows) {
                    int node = list ? list[gr] : gr;
                    float ov = fmaxf(acc2[mt][nt][q] + bv, 0.f);
                    *(__bf16*)&out[(size_t)node * 128 + col] = (__bf16)ov;
                }
            }
    }
}

// ---------------- layer 2 at roots only ----------------
__global__ __launch_bounds__(128) void k_root(const unsigned short* __restrict__ x2,
                                              const int* __restrict__ rp,
                                              const int* __restrict__ csr,
                                              const int* __restrict__ roots,
                                              const float* __restrict__ epsp,
                                              const float* __restrict__ wa,
                                              const float* __restrict__ ba,
                                              const float* __restrict__ wb,
                                              const float* __restrict__ bb,
                                              float* __restrict__ out) {
    __shared__ float hin[128];
    __shared__ float h[64];
    int r = blockIdx.x, t = threadIdx.x;
    int node = roots[r];
    float s = (1.0f + epsp[0]) * (float)(*(const __bf16*)&x2[(size_t)node * 128 + t]);
    int b = rp[node], e = rp[node + 1];
    for (int k = b; k < e; ++k)
        s += (float)(*(const __bf16*)&x2[(size_t)csr[k] * 128 + t]);
    hin[t] = s;
    __syncthreads();
    if (t < 64) {
        float a = ba[t];
        for (int k = 0; k < 128; ++k) a += hin[k] * wa[k * 64 + t];
        h[t] = fmaxf(a, 0.f);
    }
    __syncthreads();
    if (t < 64) {
        float a = bb[t];
        for (int k = 0; k < 64; ++k) a += h[k] * wb[k * 64 + t];
        out[(size_t)r * 64 + t] = a;
    }
}

extern "C" void kernel_launch(void* const* d_in, const int* in_sizes, int n_in,
                              void* d_out, int out_size, void* d_ws, size_t ws_size,
                              hipStream_t stream) {
    const float* x    = (const float*)d_in[0];
    const int*   ei   = (const int*)d_in[1];
    const int*   root = (const int*)d_in[2];
    const float* eps0 = (const float*)d_in[3];
    const float* w0a  = (const float*)d_in[4];
    const float* b0a  = (const float*)d_in[5];
    const float* w0b  = (const float*)d_in[6];
    const float* b0b  = (const float*)d_in[7];
    const float* eps1 = (const float*)d_in[8];
    const float* w1a  = (const float*)d_in[9];
    const float* b1a  = (const float*)d_in[10];
    const float* w1b  = (const float*)d_in[11];
    const float* b1b  = (const float*)d_in[12];
    const float* eps2 = (const float*)d_in[13];
    const float* w2a  = (const float*)d_in[14];
    const float* b2a  = (const float*)d_in[15];
    const float* w2b  = (const float*)d_in[16];
    const float* b2b  = (const float*)d_in[17];

    const int N  = in_sizes[0] / 128;
    const int E  = in_sizes[1] / 2;
    const int NR = in_sizes[2];
    const int MAXACT = 65536;
    const int NB = (N + 127) / 128;           // buckets of 128 nodes (782)
    const int* src = ei;
    const int* dst = ei + E;

    // ---- workspace layout ----
    char* p = (char*)d_ws;
    unsigned short* xb = (unsigned short*)p; p += (size_t)N * 128 * 2;        // 25.6 MB
    unsigned short* x1 = (unsigned short*)p; p += (size_t)N * 128 * 2;        // 25.6 MB
    // shared region: ebuf (CSR build) then ag0/x2 (layers) — disjoint in time
    char* shared0 = p;
    size_t ebuf_bytes = (size_t)NB * SUBS * CELL_CAP * 4;                     // 25.6 MB
    size_t ag0_bytes  = (size_t)N * 128 * 2;                                  // 25.6 MB
    p += (ebuf_bytes > ag0_bytes ? ebuf_bytes : ag0_bytes);
    unsigned*       ebuf = (unsigned*)shared0;
    unsigned short* ag0  = (unsigned short*)shared0;
    unsigned short* ag1  = (unsigned short*)p; p += (size_t)MAXACT * 128 * 2; // 16.8 MB
    unsigned short* wT   = (unsigned short*)p; p += 4 * 128 * 128 * 2;        // w0aT,w0bT,w1aT,w1bT
    int* rp   = (int*)p; p += (size_t)(N + 64) * 4;
    int* af   = (int*)p; p += (size_t)(N + 64) * 4;
    int* list = (int*)p; p += (size_t)(N + 64) * 4;
    int* cnt  = (int*)p; p += 256;
    int* boff = (int*)p; p += 4096;
    int* bcnt = (int*)p; p += (size_t)NB * SUBS * 16 * 4;                     // padded counters
    int* csr  = (int*)p; p += (size_t)E * 4;
    unsigned short* x2 = ag0;   // reuse after mlp0
    unsigned short* w0aT = wT;
    unsigned short* w0bT = wT + 16384;
    unsigned short* w1aT = wT + 32768;
    unsigned short* w1bT = wT + 49152;

    // ---- conversions ----
    k_cvt_x<<<(N * 128 / 8 + 255) / 256, 256, 0, stream>>>((const float4*)x, xb, (long)N * 16);
    k_cvt_w4<<<256, 256, 0, stream>>>(w0a, w0b, w1a, w1b, wT);

    // ---- bucketed CSR build ----
    hipMemsetAsync(bcnt, 0, (size_t)NB * SUBS * 16 * 4, stream);
    hipMemsetAsync(af,  0, (size_t)N * 4, stream);
    hipMemsetAsync(cnt, 0, 256, stream);
    k_scatter<<<(E + 255) / 256, 256, 0, stream>>>(src, dst, bcnt, ebuf, E);
    k_bscan<<<1, 1024, 0, stream>>>(bcnt, boff, rp, NB, N, E);
    k_build<<<NB, 256, 0, stream>>>(ebuf, bcnt, boff, rp, csr, N);

    // ---- active set ----
    k_flag<<<(NR + 255) / 256, 256, 0, stream>>>(root, NR, rp, csr, af);
    k_compact<<<(N + 255) / 256, 256, 0, stream>>>(af, list, cnt, N);

    // ---- layer 0 (all nodes) ----
    k_segsum<<<(N * 16 + 255) / 256, 256, 0, stream>>>(xb, rp, csr, ag0, nullptr, nullptr, N);
    k_mlp<<<(N + 127) / 128, 256, 0, stream>>>(xb, ag0, eps0, w0aT, b0a, w0bT, b0b,
                                               x1, nullptr, nullptr, N);
    // ---- layer 1 (active set only) ----
    k_segsum<<<(MAXACT * 16 + 255) / 256, 256, 0, stream>>>(x1, rp, csr, ag1, list, cnt, MAXACT);
    k_mlp<<<(MAXACT + 127) / 128, 256, 0, stream>>>(x1, ag1, eps1, w1aT, b1a, w1bT, b1b,
                                                    x2, list, cnt, MAXACT);
    // ---- layer 2 (roots only) ----
    k_root<<<NR, 128, 0, stream>>>(x2, rp, csr, root, eps2, w2a, b2a, w2b, b2b,
                                   (float*)d_out);
}

// Round 8
// 256.681 us; speedup vs baseline: 1.6306x; 1.1468x over previous
//
#include <hip/hip_runtime.h>

// ---------------------------------------------------------------------------
// GIN 3-layer forward on MI355X (gfx950).
//   - features/weights quantized to bf16 once per call (f32 accumulate)
//   - CSR build: LDS-binned scatter with FULL-LINE flushes:
//       k_scatter: 256 blocks x 6256 edges; 782 LDS bins (cap 38); one tail
//                  flush padded to 16-word multiples with 0xFFFFFFFF
//                  sentinels -> every global store burst is a full aligned
//                  64B line (this chip's L2 does NOT merge scattered
//                  partial-line stores: R4/R6 measured 59-83MB for 6.4MB).
//                  realcnt[] tracks true per-bucket edge counts.
//       k_bscan:   exclusive scan of realcnt -> bucket bases
//       k_build:   per-bucket histogram (skip sentinels) + scan -> rp, csr
//   - segment-sum gather: 16 lanes/node, bf16x8 loads, f32 accum
//   - MLP: MFMA 16x16x32 bf16, BM=128, 4 waves, 64KB LDS, +8-short row pad
//   - layer 1 only on active set = roots U in-neighbors(roots)
//   - layer 2 only at the 1024 roots
//   NOTE: edge packing assumes N <= 2^17 (src 17 bits, local dst 7 bits);
//         bins assume N <= 100352 (784 buckets).
// ---------------------------------------------------------------------------

typedef __bf16  bf16x8 __attribute__((ext_vector_type(8)));
typedef float   f32x4  __attribute__((ext_vector_type(4)));

#define NBINS 784     // >= (N+127)/128
#define BCAP  38      // words per LDS bin (per-bin lambda ~8)
#define CAP   8192    // words per global bucket cell (real ~2048 + pads ~2048)
#define LDR   136     // MLP LDS row stride in shorts (+8 pad)

// ---------------- conversion kernels ----------------
__global__ __launch_bounds__(256) void k_cvt_x(const float4* __restrict__ in,
                                               unsigned short* __restrict__ outb,
                                               long n8) {
    long i = (long)blockIdx.x * 256 + threadIdx.x;
    if (i >= n8) return;
    float4 a = in[2 * i], b = in[2 * i + 1];
    bf16x8 v;
    v[0] = (__bf16)a.x; v[1] = (__bf16)a.y; v[2] = (__bf16)a.z; v[3] = (__bf16)a.w;
    v[4] = (__bf16)b.x; v[5] = (__bf16)b.y; v[6] = (__bf16)b.z; v[7] = (__bf16)b.w;
    *(bf16x8*)&outb[i * 8] = v;
}

// 4 weight matrices -> transposed bf16, contiguous output (4 x 128 x 128)
__global__ __launch_bounds__(256) void k_cvt_w4(const float* __restrict__ wa,
                                                const float* __restrict__ wb,
                                                const float* __restrict__ wc,
                                                const float* __restrict__ wd,
                                                unsigned short* __restrict__ out) {
    int i = blockIdx.x * 256 + threadIdx.x;    // 65536
    int m = i >> 14, j = i & 16383;
    const float* w = (m == 0) ? wa : (m == 1) ? wb : (m == 2) ? wc : wd;
    int k = j >> 7, n = j & 127;
    *(__bf16*)&out[m * 16384 + n * 128 + k] = (__bf16)w[j];
}

// ---------------- LDS-binned scatter with full-line flush ----------------
__global__ __launch_bounds__(256) void k_scatter(const int* __restrict__ src,
                                                 const int* __restrict__ dst,
                                                 int* __restrict__ gcnt,     // NB*16 padded
                                                 int* __restrict__ realcnt,  // NB
                                                 unsigned* __restrict__ ebuf,
                                                 int e, int nb) {
    __shared__ unsigned lbuf[NBINS * BCAP];   // 119.2 KB
    __shared__ int lcnt[NBINS];
    __shared__ int sbase[NBINS];
    const int t = threadIdx.x;
    for (int b = t; b < nb; b += 256) lcnt[b] = 0;
    __syncthreads();

    const int per = (((e + 255) / 256) + 7) & ~7;   // 8-aligned slice
    const int beg = blockIdx.x * per;
    const int end = (beg + per < e) ? beg + per : e;

    // bin all edges of this block's slice into LDS
    for (int base = beg; base < end; base += 2048) {
        int i0 = base + t * 8;
        if (i0 >= end) continue;
        if (i0 + 8 <= end) {
            int4 s0 = *(const int4*)&src[i0];
            int4 s1 = *(const int4*)&src[i0 + 4];
            int4 d0 = *(const int4*)&dst[i0];
            int4 d1 = *(const int4*)&dst[i0 + 4];
            int ss[8] = {s0.x, s0.y, s0.z, s0.w, s1.x, s1.y, s1.z, s1.w};
            int dd[8] = {d0.x, d0.y, d0.z, d0.w, d1.x, d1.y, d1.z, d1.w};
#pragma unroll
            for (int q = 0; q < 8; ++q) {
                int b = dd[q] >> 7;
                int p = atomicAdd(&lcnt[b], 1);
                if (p < BCAP)
                    lbuf[b * BCAP + p] =
                        (unsigned)ss[q] | ((unsigned)(dd[q] & 127) << 17);
            }
        } else {
            int lim = (i0 + 8 < end) ? i0 + 8 : end;
            for (int i = i0; i < lim; ++i) {
                int d = dst[i];
                int b = d >> 7;
                int p = atomicAdd(&lcnt[b], 1);
                if (p < BCAP)
                    lbuf[b * BCAP + p] =
                        (unsigned)src[i] | ((unsigned)(d & 127) << 17);
            }
        }
    }
    __syncthreads();

    // phase 1: reserve cell ranges (atomic latency overlapped across threads)
    for (int b = t; b < nb; b += 256) {
        int r = lcnt[b]; if (r > BCAP) r = BCAP;
        int bb = 0;
        if (r > 0) {
            int nf = (r + 15) & ~15;
            bb = atomicAdd(&gcnt[b * 16], nf);
            atomicAdd(&realcnt[b], r);
        }
        sbase[b] = bb;
    }
    __syncthreads();

    // phase 2: cooperative full-line copies (16-lane group per bin)
    const int wave = t >> 6, lane = t & 63;
    const int gidx = wave * 4 + (lane >> 4), sub = lane & 15;
    for (int b = gidx; b < nb; b += 16) {
        int r = lcnt[b]; if (r > BCAP) r = BCAP;
        if (r == 0) continue;
        int nf = (r + 15) & ~15;
        int base2 = sbase[b];
        unsigned* cell = ebuf + (size_t)b * CAP;
        for (int j = sub; j < nf; j += 16) {
            unsigned v = (j < r) ? lbuf[b * BCAP + j] : 0xFFFFFFFFu;
            if (base2 + j < CAP) cell[base2 + j] = v;
        }
    }
}

// one block: exclusive scan of nb real bucket counts (nb <= 1024); rp[n]=e
__global__ __launch_bounds__(1024) void k_bscan(const int* __restrict__ realcnt,
                                                int* __restrict__ boff,
                                                int* __restrict__ rp,
                                                int nb, int n, int e) {
    __shared__ int sh[1024];
    int t = threadIdx.x;
    sh[t] = (t < nb) ? realcnt[t] : 0;
    __syncthreads();
    for (int off = 1; off < 1024; off <<= 1) {
        int u = (t >= off) ? sh[t - off] : 0;
        __syncthreads();
        sh[t] += u;
        __syncthreads();
    }
    if (t < nb) boff[t] = (t == 0) ? 0 : sh[t - 1];
    if (t == 0) rp[n] = e;
}

// one block per bucket: histogram (skip sentinels) -> scan -> rp -> csr
__global__ __launch_bounds__(256) void k_build(const unsigned* __restrict__ ebuf,
                                               const int* __restrict__ gcnt,
                                               const int* __restrict__ boff,
                                               int* __restrict__ rp,
                                               int* __restrict__ csr, int n) {
    __shared__ int bins[128];
    __shared__ int incl[128];
    __shared__ int cur[128];
    int b = blockIdx.x, t = threadIdx.x;
    if (t < 128) bins[t] = 0;
    __syncthreads();
    int c = gcnt[b * 16]; if (c > CAP) c = CAP;
    const unsigned* seg = ebuf + ((size_t)b * CAP);
    for (int j = t; j < c; j += 256) {
        unsigned w = seg[j];
        if (w != 0xFFFFFFFFu) atomicAdd(&bins[(w >> 17) & 127], 1);
    }
    __syncthreads();
    if (t < 128) incl[t] = bins[t];
    __syncthreads();
    for (int off = 1; off < 128; off <<= 1) {
        int u = (t < 128 && t >= off) ? incl[t - off] : 0;
        __syncthreads();
        if (t < 128) incl[t] += u;
        __syncthreads();
    }
    int base = boff[b];
    if (t < 128) {
        int ex = (t == 0) ? 0 : incl[t - 1];
        cur[t] = ex;
        int node = b * 128 + t;
        if (node < n) rp[node] = base + ex;
    }
    __syncthreads();
    for (int j = t; j < c; j += 256) {
        unsigned w = seg[j];
        if (w != 0xFFFFFFFFu) {
            int slot = atomicAdd(&cur[(w >> 17) & 127], 1);
            csr[base + slot] = (int)(w & 0x1FFFF);
        }
    }
}

// ---------------- active set (roots + their in-neighbors) ----------------
__global__ void k_flag(const int* __restrict__ roots, int nr,
                       const int* __restrict__ rp, const int* __restrict__ csr,
                       int* __restrict__ af) {
    int i = blockIdx.x * blockDim.x + threadIdx.x;
    if (i >= nr) return;
    int r = roots[i];
    af[r] = 1;
    int e = rp[r + 1];
    for (int k = rp[r]; k < e; ++k) af[csr[k]] = 1;
}

__global__ void k_compact(const int* __restrict__ af, int* __restrict__ list,
                          int* __restrict__ cnt, int n) {
    int i = blockIdx.x * blockDim.x + threadIdx.x;
    if (i < n && af[i]) {
        int p = atomicAdd(cnt, 1);
        list[p] = i;
    }
}

// ---------------- segment sum (bf16 in, bf16 out, f32 accumulate) ----------
__global__ __launch_bounds__(256) void k_segsum(const unsigned short* __restrict__ xb,
                                                const int* __restrict__ rp,
                                                const int* __restrict__ csr,
                                                unsigned short* __restrict__ agg,
                                                const int* __restrict__ list,
                                                const int* __restrict__ cntp, int n) {
    int gid = blockIdx.x * 256 + threadIdx.x;
    int j = gid >> 4, lane = gid & 15;
    int rows = n;
    if (cntp) { int c = *cntp; rows = c < n ? c : n; }
    if (j >= rows) return;
    int node = list ? list[j] : j;
    int b = rp[node], e = rp[node + 1];
    float s0[8], s1[8];
#pragma unroll
    for (int q = 0; q < 8; ++q) { s0[q] = 0.f; s1[q] = 0.f; }
    int k = b;
    for (; k + 1 < e; k += 2) {
        bf16x8 v0 = *(const bf16x8*)&xb[(size_t)csr[k]     * 128 + lane * 8];
        bf16x8 v1 = *(const bf16x8*)&xb[(size_t)csr[k + 1] * 128 + lane * 8];
#pragma unroll
        for (int q = 0; q < 8; ++q) { s0[q] += (float)v0[q]; s1[q] += (float)v1[q]; }
    }
    if (k < e) {
        bf16x8 v0 = *(const bf16x8*)&xb[(size_t)csr[k] * 128 + lane * 8];
#pragma unroll
        for (int q = 0; q < 8; ++q) s0[q] += (float)v0[q];
    }
    bf16x8 o;
#pragma unroll
    for (int q = 0; q < 8; ++q) o[q] = (__bf16)(s0[q] + s1[q]);
    *(bf16x8*)&agg[(size_t)j * 128 + lane * 8] = o;
}

// ---------------- fused MLP: relu( relu(z@w1+b1) @ w2 + b2 ), z=(1+eps)x+agg
__global__ __launch_bounds__(256) void k_mlp(const unsigned short* __restrict__ xb,
                                             const unsigned short* __restrict__ aggb,
                                             const float* __restrict__ epsp,
                                             const unsigned short* __restrict__ w1T,
                                             const float* __restrict__ b1,
                                             const unsigned short* __restrict__ w2T,
                                             const float* __restrict__ b2,
                                             unsigned short* __restrict__ out,
                                             const int* __restrict__ list,
                                             const int* __restrict__ cntp, int nrows) {
    __shared__ unsigned short zt  [128 * LDR];   // 34.8 KB
    __shared__ unsigned short wbuf[128 * LDR];   // 34.8 KB
    const int t = threadIdx.x;
    int rows = nrows;
    if (cntp) { int c = *cntp; rows = c < nrows ? c : nrows; }
    const int row0 = blockIdx.x * 128;
    if (row0 >= rows) return;
    const float epsv = 1.0f + epsp[0];

    for (int i = t; i < 2048; i += 256) {
        int r = i >> 4, c = i & 15;
        *(bf16x8*)&wbuf[r * LDR + c * 8] = *(const bf16x8*)&w1T[i * 8];
    }
    for (int i = t; i < 2048; i += 256) {
        int r = i >> 4, c = i & 15;
        int g = row0 + r;
        bf16x8 zv;
        if (g < rows) {
            int node = list ? list[g] : g;
            bf16x8 xv = *(const bf16x8*)&xb  [(size_t)node * 128 + c * 8];
            bf16x8 av = *(const bf16x8*)&aggb[(size_t)g    * 128 + c * 8];
#pragma unroll
            for (int q = 0; q < 8; ++q)
                zv[q] = (__bf16)(epsv * (float)xv[q] + (float)av[q]);
        } else {
#pragma unroll
            for (int q = 0; q < 8; ++q) zv[q] = (__bf16)0.0f;
        }
        *(bf16x8*)&zt[r * LDR + c * 8] = zv;
    }
    __syncthreads();

    const int lane = t & 63;
    const int wm = (t >> 7) & 1, wn = (t >> 6) & 1;
    const int lr = lane & 15, lk = lane >> 4;

    f32x4 zero4 = {0.f, 0.f, 0.f, 0.f};
    f32x4 acc[4][4];
#pragma unroll
    for (int mt = 0; mt < 4; ++mt)
#pragma unroll
        for (int nt = 0; nt < 4; ++nt) acc[mt][nt] = zero4;

#pragma unroll
    for (int kb = 0; kb < 4; ++kb) {
        const int c = kb * 4 + lk;
        bf16x8 a[4];
#pragma unroll
        for (int mt = 0; mt < 4; ++mt)
            a[mt] = *(const bf16x8*)&zt[(wm * 64 + mt * 16 + lr) * LDR + c * 8];
#pragma unroll
        for (int nt = 0; nt < 4; ++nt) {
            bf16x8 b = *(const bf16x8*)&wbuf[(wn * 64 + nt * 16 + lr) * LDR + c * 8];
#pragma unroll
            for (int mt = 0; mt < 4; ++mt)
                acc[mt][nt] = __builtin_amdgcn_mfma_f32_16x16x32_bf16(a[mt], b, acc[mt][nt], 0, 0, 0);
        }
    }
    __syncthreads();

    // h = relu(acc + b1) -> zt (in place); stage w2 -> wbuf
#pragma unroll
    for (int nt = 0; nt < 4; ++nt) {
        int col = wn * 64 + nt * 16 + lr;
        float bv = b1[col];
#pragma unroll
        for (int mt = 0; mt < 4; ++mt)
#pragma unroll
            for (int q = 0; q < 4; ++q) {
                int hr = wm * 64 + mt * 16 + lk * 4 + q;
                float hv = fmaxf(acc[mt][nt][q] + bv, 0.f);
                *(__bf16*)&zt[hr * LDR + col] = (__bf16)hv;
            }
    }
    for (int i = t; i < 2048; i += 256) {
        int r = i >> 4, c = i & 15;
        *(bf16x8*)&wbuf[r * LDR + c * 8] = *(const bf16x8*)&w2T[i * 8];
    }
    __syncthreads();

    f32x4 acc2[4][4];
#pragma unroll
    for (int mt = 0; mt < 4; ++mt)
#pragma unroll
        for (int nt = 0; nt < 4; ++nt) acc2[mt][nt] = zero4;
#pragma unroll
    for (int kb = 0; kb < 4; ++kb) {
        const int c = kb * 4 + lk;
        bf16x8 a[4];
#pragma unroll
        for (int mt = 0; mt < 4; ++mt)
            a[mt] = *(const bf16x8*)&zt[(wm * 64 + mt * 16 + lr) * LDR + c * 8];
#pragma unroll
        for (int nt = 0; nt < 4; ++nt) {
            bf16x8 b = *(const bf16x8*)&wbuf[(wn * 64 + nt * 16 + lr) * LDR + c * 8];
#pragma unroll
            for (int mt = 0; mt < 4; ++mt)
                acc2[mt][nt] = __builtin_amdgcn_mfma_f32_16x16x32_bf16(a[mt], b, acc2[mt][nt], 0, 0, 0);
        }
    }

#pragma unroll
    for (int nt = 0; nt < 4; ++nt) {
        int col = wn * 64 + nt * 16 + lr;
        float bv = b2[col];
#pragma unroll
        for (int mt = 0; mt < 4; ++mt)
#pragma unroll
            for (int q = 0; q < 4; ++q) {
                int gr = row0 + wm * 64 + mt * 16 + lk * 4 + q;
                if (gr < rows) {
                    int node = list ? list[gr] : gr;
                    float ov = fmaxf(acc2[mt][nt][q] + bv, 0.f);
                    *(__bf16*)&out[(size_t)node * 128 + col] = (__bf16)ov;
                }
            }
    }
}

// ---------------- layer 2 at roots only ----------------
__global__ __launch_bounds__(128) void k_root(const unsigned short* __restrict__ x2,
                                              const int* __restrict__ rp,
                                              const int* __restrict__ csr,
                                              const int* __restrict__ roots,
                                              const float* __restrict__ epsp,
                                              const float* __restrict__ wa,
                                              const float* __restrict__ ba,
                                              const float* __restrict__ wb,
                                              const float* __restrict__ bb,
                                              float* __restrict__ out) {
    __shared__ float hin[128];
    __shared__ float h[64];
    int r = blockIdx.x, t = threadIdx.x;
    int node = roots[r];
    float s = (1.0f + epsp[0]) * (float)(*(const __bf16*)&x2[(size_t)node * 128 + t]);
    int b = rp[node], e = rp[node + 1];
    for (int k = b; k < e; ++k)
        s += (float)(*(const __bf16*)&x2[(size_t)csr[k] * 128 + t]);
    hin[t] = s;
    __syncthreads();
    if (t < 64) {
        float a = ba[t];
        for (int k = 0; k < 128; ++k) a += hin[k] * wa[k * 64 + t];
        h[t] = fmaxf(a, 0.f);
    }
    __syncthreads();
    if (t < 64) {
        float a = bb[t];
        for (int k = 0; k < 64; ++k) a += h[k] * wb[k * 64 + t];
        out[(size_t)r * 64 + t] = a;
    }
}

extern "C" void kernel_launch(void* const* d_in, const int* in_sizes, int n_in,
                              void* d_out, int out_size, void* d_ws, size_t ws_size,
                              hipStream_t stream) {
    const float* x    = (const float*)d_in[0];
    const int*   ei   = (const int*)d_in[1];
    const int*   root = (const int*)d_in[2];
    const float* eps0 = (const float*)d_in[3];
    const float* w0a  = (const float*)d_in[4];
    const float* b0a  = (const float*)d_in[5];
    const float* w0b  = (const float*)d_in[6];
    const float* b0b  = (const float*)d_in[7];
    const float* eps1 = (const float*)d_in[8];
    const float* w1a  = (const float*)d_in[9];
    const float* b1a  = (const float*)d_in[10];
    const float* w1b  = (const float*)d_in[11];
    const float* b1b  = (const float*)d_in[12];
    const float* eps2 = (const float*)d_in[13];
    const float* w2a  = (const float*)d_in[14];
    const float* b2a  = (const float*)d_in[15];
    const float* w2b  = (const float*)d_in[16];
    const float* b2b  = (const float*)d_in[17];

    const int N  = in_sizes[0] / 128;
    const int E  = in_sizes[1] / 2;
    const int NR = in_sizes[2];
    const int MAXACT = 65536;
    const int NB = (N + 127) / 128;           // buckets of 128 nodes (782)
    const int* src = ei;
    const int* dst = ei + E;

    // ---- workspace layout ----
    char* p = (char*)d_ws;
    unsigned short* xb = (unsigned short*)p; p += (size_t)N * 128 * 2;        // 25.6 MB
    unsigned short* x1 = (unsigned short*)p; p += (size_t)N * 128 * 2;        // 25.6 MB
    // shared region: ebuf (CSR build) then ag0/x2 (layers) — disjoint in time
    char* shared0 = p;
    size_t ebuf_bytes = (size_t)NB * CAP * 4;                                 // 25.6 MB
    size_t ag0_bytes  = (size_t)N * 128 * 2;                                  // 25.6 MB
    p += (ebuf_bytes > ag0_bytes ? ebuf_bytes : ag0_bytes);
    unsigned*       ebuf = (unsigned*)shared0;
    unsigned short* ag0  = (unsigned short*)shared0;
    unsigned short* ag1  = (unsigned short*)p; p += (size_t)MAXACT * 128 * 2; // 16.8 MB
    unsigned short* wT   = (unsigned short*)p; p += 4 * 128 * 128 * 2;
    int* rp      = (int*)p; p += (size_t)(N + 64) * 4;
    int* af      = (int*)p; p += (size_t)(N + 64) * 4;
    int* list    = (int*)p; p += (size_t)(N + 64) * 4;
    int* cnt     = (int*)p; p += 256;
    int* boff    = (int*)p; p += 4096;
    int* gcnt    = (int*)p; p += (size_t)NB * 16 * 4;      // 64B-padded counters
    int* realcnt = (int*)p; p += (size_t)(NB + 64) * 4;
    int* csr     = (int*)p; p += (size_t)E * 4;
    unsigned short* x2 = ag0;   // reuse after mlp0
    unsigned short* w0aT = wT;
    unsigned short* w0bT = wT + 16384;
    unsigned short* w1aT = wT + 32768;
    unsigned short* w1bT = wT + 49152;

    // ---- conversions ----
    k_cvt_x<<<(N * 128 / 8 + 255) / 256, 256, 0, stream>>>((const float4*)x, xb, (long)N * 16);
    k_cvt_w4<<<256, 256, 0, stream>>>(w0a, w0b, w1a, w1b, wT);

    // ---- CSR build ----
    hipMemsetAsync(gcnt, 0, (size_t)NB * 16 * 4, stream);
    hipMemsetAsync(realcnt, 0, (size_t)NB * 4, stream);
    hipMemsetAsync(af,  0, (size_t)N * 4, stream);
    hipMemsetAsync(cnt, 0, 256, stream);
    k_scatter<<<256, 256, 0, stream>>>(src, dst, gcnt, realcnt, ebuf, E, NB);
    k_bscan<<<1, 1024, 0, stream>>>(realcnt, boff, rp, NB, N, E);
    k_build<<<NB, 256, 0, stream>>>(ebuf, gcnt, boff, rp, csr, N);

    // ---- active set ----
    k_flag<<<(NR + 255) / 256, 256, 0, stream>>>(root, NR, rp, csr, af);
    k_compact<<<(N + 255) / 256, 256, 0, stream>>>(af, list, cnt, N);

    // ---- layer 0 (all nodes) ----
    k_segsum<<<(N * 16 + 255) / 256, 256, 0, stream>>>(xb, rp, csr, ag0, nullptr, nullptr, N);
    k_mlp<<<(N + 127) / 128, 256, 0, stream>>>(xb, ag0, eps0, w0aT, b0a, w0bT, b0b,
                                               x1, nullptr, nullptr, N);
    // ---- layer 1 (active set only) ----
    k_segsum<<<(MAXACT * 16 + 255) / 256, 256, 0, stream>>>(x1, rp, csr, ag1, list, cnt, MAXACT);
    k_mlp<<<(MAXACT + 127) / 128, 256, 0, stream>>>(x1, ag1, eps1, w1aT, b1a, w1bT, b1b,
                                                    x2, list, cnt, MAXACT);
    // ---- layer 2 (roots only) ----
    k_root<<<NR, 128, 0, stream>>>(x2, rp, csr, root, eps2, w2a, b2a, w2b, b2b,
                                   (float*)d_out);
}